// Round 1
// baseline (1706.006 us; speedup 1.0000x reference)
//
#include <hip/hip_runtime.h>
#include <stdint.h>

#define DM     2048
#define NHE    16
#define DFF    8192
#define NBATCH 2
#define SEQ    2048
#define NTOK   4096
#define HD     128
#define NVOCAB 32000

typedef __attribute__((ext_vector_type(8))) short short8;
typedef __attribute__((ext_vector_type(4))) float f32x4;
typedef __attribute__((ext_vector_type(4))) unsigned short u16x4;

static __device__ __forceinline__ unsigned short f2b(float f) {
  union { float f; uint32_t u; } v; v.f = f;
  return (unsigned short)((v.u + 0x7FFFu + ((v.u >> 16) & 1u)) >> 16);
}

static __device__ __forceinline__ void gload16(const void* g, void* l) {
  __builtin_amdgcn_global_load_lds(
      (const __attribute__((address_space(1))) unsigned int*)g,
      (__attribute__((address_space(3))) unsigned int*)l, 16, 0, 0);
}

// ---------------------------------------------------------------- conversions
__global__ void k_f32_to_bf16(const float* __restrict__ in,
                              unsigned short* __restrict__ out, int nq) {
  int i = blockIdx.x * blockDim.x + threadIdx.x;
  int stride = gridDim.x * blockDim.x;
  for (; i < nq; i += stride) {
    float4 v = ((const float4*)in)[i];
    u16x4 o;
    o.x = f2b(v.x); o.y = f2b(v.y); o.z = f2b(v.z); o.w = f2b(v.w);
    ((u16x4*)out)[i] = o;
  }
}

// ---------------------------------------------------------------- embedding
__global__ void k_embed(const int* __restrict__ tok,
                        const float* __restrict__ emb, float* __restrict__ x) {
  int n = blockIdx.x;
  int t = tok[n];
  const float4* src = (const float4*)(emb + (size_t)t * DM);
  float4* dst = (float4*)(x + (size_t)n * DM);
  for (int i = threadIdx.x; i < DM / 4; i += blockDim.x) dst[i] = src[i];
}

// ---------------------------------------------------------------- rmsnorm
__global__ void k_rmsnorm(const float* __restrict__ x, const float* __restrict__ wt,
                          unsigned short* __restrict__ out) {
  int n = blockIdx.x;
  const float* row = x + (size_t)n * DM;
  float ss = 0.f;
  #pragma unroll
  for (int it = 0; it < 2; ++it) {
    int i = threadIdx.x * 4 + it * 1024;
    float4 v = *(const float4*)(row + i);
    ss += v.x * v.x + v.y * v.y + v.z * v.z + v.w * v.w;
  }
  #pragma unroll
  for (int m = 1; m < 64; m <<= 1) ss += __shfl_xor(ss, m);
  __shared__ float p[4];
  if ((threadIdx.x & 63) == 0) p[threadIdx.x >> 6] = ss;
  __syncthreads();
  float inv = rsqrtf((p[0] + p[1] + p[2] + p[3]) * (1.f / DM) + 1e-6f);
  #pragma unroll
  for (int it = 0; it < 2; ++it) {
    int i = threadIdx.x * 4 + it * 1024;
    float4 v = *(const float4*)(row + i);
    float4 w4 = *(const float4*)(wt + i);
    u16x4 o;
    o.x = f2b(v.x * w4.x * inv); o.y = f2b(v.y * w4.y * inv);
    o.z = f2b(v.z * w4.z * inv); o.w = f2b(v.w * w4.w * inv);
    *(u16x4*)(out + (size_t)n * DM + i) = o;
  }
}

// ---------------------------------------------------------------- GEMM (NT)
// C[M,N] = A[M,K] * B[N,K]^T ; A,B bf16 row-major K-contig; f32 accum.
// 128x128 tile, BK=64, 4 waves (2x2), 4x4 16x16x32 frags per wave.
// LDS XOR swizzle: byte addr = row*128 + (colbytes ^ ((row&7)<<4)), staged via
// pre-swizzled global source through global_load_lds (linear dest).
#define EPI_BF16  0
#define EPI_RESID 1
#define EPI_SILU  2
#define EPI_F32   3

template <int EPI>
__launch_bounds__(256)
__global__ void k_gemm_nt(const unsigned short* __restrict__ A,
                          const unsigned short* __restrict__ Bm,
                          int M, int N, int K,
                          float* __restrict__ Cf, unsigned short* __restrict__ Cb,
                          const float* __restrict__ R) {
  __shared__ unsigned short a_lds[128 * 64];
  __shared__ unsigned short b_lds[128 * 64];
  int nbn = N >> 7;
  int nwg = gridDim.x;
  int bid = blockIdx.x;
  int cpx = nwg >> 3;                       // all grids are multiples of 8
  bid = (bid & 7) * cpx + (bid >> 3);       // XCD-bijective swizzle
  int bm = bid / nbn, bn = bid % nbn;
  int t = threadIdx.x, w = t >> 6, lane = t & 63;
  int wr = w >> 1, wc = w & 1;
  int g = lane >> 4, l15 = lane & 15;

  f32x4 acc[4][4] = {};

  size_t abase = (size_t)(bm * 128) * K;
  size_t bbase = (size_t)(bn * 128) * K;
  int nkt = K >> 6;

  for (int kt = 0; kt < nkt; ++kt) {
    int k0 = kt << 6;
    #pragma unroll
    for (int i = 0; i < 4; ++i) {
      int pos = ((i * 4 + w) << 10) + lane * 16;   // byte pos in 16KB tile
      int row = pos >> 7;
      int csw = pos & 127;
      int csrc = csw ^ ((row & 7) << 4);
      char* ldst_a = (char*)a_lds + ((i * 4 + w) << 10);
      char* ldst_b = (char*)b_lds + ((i * 4 + w) << 10);
      gload16(A + abase + (size_t)row * K + k0 + (csrc >> 1), ldst_a);
      gload16(Bm + bbase + (size_t)row * K + k0 + (csrc >> 1), ldst_b);
    }
    __syncthreads();
    #pragma unroll
    for (int kk = 0; kk < 2; ++kk) {
      short8 af[4], bfr[4];
      #pragma unroll
      for (int mm = 0; mm < 4; ++mm) {
        int row = wr * 64 + mm * 16 + l15;
        int col = kk * 64 + g * 16;
        af[mm] = *(const short8*)((const char*)a_lds + row * 128 + (col ^ ((row & 7) << 4)));
      }
      #pragma unroll
      for (int nn = 0; nn < 4; ++nn) {
        int row = wc * 64 + nn * 16 + l15;
        int col = kk * 64 + g * 16;
        bfr[nn] = *(const short8*)((const char*)b_lds + row * 128 + (col ^ ((row & 7) << 4)));
      }
      #pragma unroll
      for (int mm = 0; mm < 4; ++mm)
        #pragma unroll
        for (int nn = 0; nn < 4; ++nn)
          acc[mm][nn] = __builtin_amdgcn_mfma_f32_16x16x32_bf16(af[mm], bfr[nn], acc[mm][nn], 0, 0, 0);
    }
    __syncthreads();
  }

  #pragma unroll
  for (int mm = 0; mm < 4; ++mm) {
    #pragma unroll
    for (int nn = 0; nn < 4; ++nn) {
      #pragma unroll
      for (int r = 0; r < 4; ++r) {
        int grow = bm * 128 + wr * 64 + mm * 16 + g * 4 + r;
        int gcol = bn * 128 + wc * 64 + nn * 16 + l15;
        size_t off = (size_t)grow * N + gcol;
        float v = acc[mm][nn][r];
        if (EPI == EPI_BF16) {
          Cb[off] = f2b(v);
        } else if (EPI == EPI_RESID) {
          Cf[off] = R[off] + v;
        } else if (EPI == EPI_SILU) {
          float s = 1.f / (1.f + __expf(-v));
          Cb[off] = f2b(v * s);
        } else {
          Cf[off] = v;
        }
      }
    }
  }
}

// ---------------------------------------------------------------- V transpose
// v [NTOK][DM] bf16 -> vt [32 pairs][HD][SEQ] bf16
__global__ void k_transpose_v(const unsigned short* __restrict__ v,
                              unsigned short* __restrict__ vt) {
  __shared__ unsigned short tile[64][136];
  int pr = blockIdx.x >> 5;     // pair
  int st = blockIdx.x & 31;     // s-tile of 64
  int bb = pr >> 4, h = pr & 15;
  int row = threadIdx.x >> 2;   // 0..63 (s within tile)
  int cq = threadIdx.x & 3;
  const unsigned short* src =
      v + (size_t)(bb * SEQ + st * 64 + row) * DM + h * HD + cq * 32;
  #pragma unroll
  for (int j = 0; j < 4; ++j)
    *(short8*)&tile[row][cq * 32 + j * 8] = *(const short8*)(src + j * 8);
  __syncthreads();
  int d = threadIdx.x >> 1;     // 0..127
  int sh = threadIdx.x & 1;     // s-half of 32
  unsigned short tmp[32];
  #pragma unroll
  for (int j = 0; j < 32; ++j) tmp[j] = tile[sh * 32 + j][d];
  unsigned short* dst = vt + ((size_t)pr * HD + d) * SEQ + st * 64 + sh * 32;
  #pragma unroll
  for (int j = 0; j < 4; ++j)
    *(short8*)(dst + j * 8) = *(const short8*)&tmp[j * 8];
}

// ---------------------------------------------------------------- attention
// One block = (pair, q-tile of 128). 4 waves, wave owns 32 q rows.
// KV tiles of 64. K staged [64][256B] swizzled; VT staged [128][128B] swizzled.
// Online softmax in registers; P through per-wave swizzled LDS.
__launch_bounds__(256)
__global__ void k_attn(const unsigned short* __restrict__ q,
                       const unsigned short* __restrict__ k,
                       const unsigned short* __restrict__ vt,
                       unsigned short* __restrict__ ao) {
  __shared__ unsigned short k_lds[64 * 128];
  __shared__ unsigned short vt_lds[128 * 64];
  __shared__ unsigned short p_lds[4][32 * 64];

  int bid = blockIdx.x;
  int pr = bid >> 4;
  int qt = 15 - (bid & 15);          // heavy tiles first
  int bb = pr >> 4, h = pr & 15;
  int t = threadIdx.x, w = t >> 6, lane = t & 63;
  int g = lane >> 4, l15 = lane & 15;
  const float SCL = 0.08838834764831845f * 1.4426950408889634f; // 1/sqrt(128)*log2e

  int qrow_base = qt * 128 + w * 32;
  short8 aq[2][4];
  #pragma unroll
  for (int mm = 0; mm < 2; ++mm) {
    size_t n = (size_t)(bb * SEQ + qrow_base + mm * 16 + l15);
    #pragma unroll
    for (int kk = 0; kk < 4; ++kk)
      aq[mm][kk] = *(const short8*)(q + n * DM + h * HD + kk * 32 + g * 8);
  }

  f32x4 o[2][8] = {};
  float m2[2][4], ls[2][4];
  #pragma unroll
  for (int mm = 0; mm < 2; ++mm)
    #pragma unroll
    for (int r = 0; r < 4; ++r) { m2[mm][r] = -1e30f; ls[mm][r] = 0.f; }

  int nkv = 2 * qt + 2;
  for (int kvt = 0; kvt < nkv; ++kvt) {
    // ---- stage K and VT tiles (pre-swizzled source, linear LDS dest)
    #pragma unroll
    for (int i = 0; i < 4; ++i) {
      int pos = ((i * 4 + w) << 10) + lane * 16;
      {
        int row = pos >> 8, csw = pos & 255;
        int csrc = csw ^ ((row & 7) << 4);
        gload16(k + (size_t)(bb * SEQ + kvt * 64 + row) * DM + h * HD + (csrc >> 1),
                (char*)k_lds + ((i * 4 + w) << 10));
      }
      {
        int row = pos >> 7, csw = pos & 127;
        int csrc = csw ^ ((row & 7) << 4);
        gload16(vt + ((size_t)pr * HD + row) * SEQ + kvt * 64 + (csrc >> 1),
                (char*)vt_lds + ((i * 4 + w) << 10));
      }
    }
    __syncthreads();

    // ---- S = Q K^T
    f32x4 s[2][4] = {};
    #pragma unroll
    for (int kk = 0; kk < 4; ++kk) {
      short8 bk[4];
      #pragma unroll
      for (int nn = 0; nn < 4; ++nn) {
        int row = nn * 16 + l15;
        int col = kk * 64 + g * 16;
        bk[nn] = *(const short8*)((const char*)k_lds + row * 256 + (col ^ ((row & 7) << 4)));
      }
      #pragma unroll
      for (int mm = 0; mm < 2; ++mm)
        #pragma unroll
        for (int nn = 0; nn < 4; ++nn)
          s[mm][nn] = __builtin_amdgcn_mfma_f32_16x16x32_bf16(aq[mm][kk], bk[nn], s[mm][nn], 0, 0, 0);
    }

    // ---- mask + online softmax + P to LDS
    bool diag = (kvt >= 2 * qt);
    #pragma unroll
    for (int mm = 0; mm < 2; ++mm) {
      float mx[4] = {-1e30f, -1e30f, -1e30f, -1e30f};
      #pragma unroll
      for (int nn = 0; nn < 4; ++nn)
        #pragma unroll
        for (int r = 0; r < 4; ++r) {
          float sv = s[mm][nn][r] * SCL;
          if (diag) {
            int kvg = kvt * 64 + nn * 16 + l15;
            int qg = qrow_base + mm * 16 + g * 4 + r;
            if (kvg > qg) sv = -1e30f;
          }
          s[mm][nn][r] = sv;
          mx[r] = fmaxf(mx[r], sv);
        }
      #pragma unroll
      for (int r = 0; r < 4; ++r) {
        mx[r] = fmaxf(mx[r], __shfl_xor(mx[r], 1));
        mx[r] = fmaxf(mx[r], __shfl_xor(mx[r], 2));
        mx[r] = fmaxf(mx[r], __shfl_xor(mx[r], 4));
        mx[r] = fmaxf(mx[r], __shfl_xor(mx[r], 8));
        float mn = fmaxf(m2[mm][r], mx[r]);
        float al = exp2f(m2[mm][r] - mn);
        m2[mm][r] = mn;
        ls[mm][r] *= al;
        #pragma unroll
        for (int dd = 0; dd < 8; ++dd) o[mm][dd][r] *= al;
      }
      #pragma unroll
      for (int nn = 0; nn < 4; ++nn)
        #pragma unroll
        for (int r = 0; r < 4; ++r) {
          float pv = exp2f(s[mm][nn][r] - m2[mm][r]);
          ls[mm][r] += pv;
          int row = mm * 16 + g * 4 + r;
          int colb = (nn * 16 + l15) * 2;
          *(unsigned short*)((char*)p_lds[w] + row * 128 + (colb ^ (((row >> 1) & 7) << 4))) = f2b(pv);
        }
    }

    // ---- O += P V  (B operand from VT)
    #pragma unroll
    for (int kk = 0; kk < 2; ++kk) {
      short8 pf[2], vf[8];
      #pragma unroll
      for (int mm = 0; mm < 2; ++mm) {
        int row = mm * 16 + l15;
        int col = kk * 64 + g * 16;
        pf[mm] = *(const short8*)((const char*)p_lds[w] + row * 128 + (col ^ (((row >> 1) & 7) << 4)));
      }
      #pragma unroll
      for (int dd = 0; dd < 8; ++dd) {
        int row = dd * 16 + l15;
        int col = kk * 64 + g * 16;
        vf[dd] = *(const short8*)((const char*)vt_lds + row * 128 + (col ^ ((row & 7) << 4)));
      }
      #pragma unroll
      for (int mm = 0; mm < 2; ++mm)
        #pragma unroll
        for (int dd = 0; dd < 8; ++dd)
          o[mm][dd] = __builtin_amdgcn_mfma_f32_16x16x32_bf16(pf[mm], vf[dd], o[mm][dd], 0, 0, 0);
    }
    __syncthreads();
  }

  // ---- finalize
  #pragma unroll
  for (int mm = 0; mm < 2; ++mm) {
    float inv[4];
    #pragma unroll
    for (int r = 0; r < 4; ++r) {
      float tt = ls[mm][r];
      tt += __shfl_xor(tt, 1);
      tt += __shfl_xor(tt, 2);
      tt += __shfl_xor(tt, 4);
      tt += __shfl_xor(tt, 8);
      inv[r] = 1.f / tt;
    }
    #pragma unroll
    for (int dd = 0; dd < 8; ++dd)
      #pragma unroll
      for (int r = 0; r < 4; ++r) {
        size_t n = (size_t)(bb * SEQ + qrow_base + mm * 16 + g * 4 + r);
        int col = h * HD + dd * 16 + l15;
        ao[n * DM + col] = f2b(o[mm][dd][r] * inv[r]);
      }
  }
}

// ---------------------------------------------------------------- launch
extern "C" void kernel_launch(void* const* d_in, const int* in_sizes, int n_in,
                              void* d_out, int out_size, void* d_ws, size_t ws_size,
                              hipStream_t stream) {
  const int* tokens = (const int*)d_in[0];
  const float* tok_emb = (const float*)d_in[1];
  const float* wq = (const float*)d_in[2];
  const float* wk = (const float*)d_in[3];
  const float* wv = (const float*)d_in[4];
  const float* wo = (const float*)d_in[5];
  const float* attn_nw = (const float*)d_in[6];
  const float* ffn_nw = (const float*)d_in[7];
  const float* final_nw = (const float*)d_in[8];
  const float* w1 = (const float*)d_in[9];
  const float* w2 = (const float*)d_in[10];
  const float* out_proj = (const float*)d_in[11];
  float* out = (float*)d_out;

  char* ws = (char*)d_ws;
  size_t off = 0;
  auto alloc = [&](size_t bytes) -> char* {
    char* p = ws + off;
    off += (bytes + 255) & ~(size_t)255;
    return p;
  };
  unsigned short* wq_b = (unsigned short*)alloc((size_t)DM * DM * 2);
  unsigned short* wk_b = (unsigned short*)alloc((size_t)DM * DM * 2);
  unsigned short* wv_b = (unsigned short*)alloc((size_t)DM * DM * 2);
  unsigned short* wo_b = (unsigned short*)alloc((size_t)DM * DM * 2);
  unsigned short* w1_b = (unsigned short*)alloc((size_t)DFF * DM * 2);
  unsigned short* w2_b = (unsigned short*)alloc((size_t)DM * DFF * 2);
  unsigned short* wop_b = (unsigned short*)alloc((size_t)NVOCAB * DM * 2);
  float* x = (float*)alloc((size_t)NTOK * DM * 4);
  unsigned short* xn = (unsigned short*)alloc((size_t)NTOK * DM * 2);
  unsigned short* q_b = (unsigned short*)alloc((size_t)NTOK * DM * 2);
  unsigned short* k_b = (unsigned short*)alloc((size_t)NTOK * DM * 2);
  unsigned short* v_b = (unsigned short*)alloc((size_t)NTOK * DM * 2);
  unsigned short* vt_b = (unsigned short*)alloc((size_t)NTOK * DM * 2);
  unsigned short* ao_b = (unsigned short*)alloc((size_t)NTOK * DM * 2);
  unsigned short* h1_b = q_b;  // alias: q/k/v/vt dead when h1 is written

  auto conv = [&](const float* src, unsigned short* dst, size_t n) {
    int nq = (int)(n / 4);
    int grid = (nq + 255) / 256;
    if (grid > 4096) grid = 4096;
    k_f32_to_bf16<<<grid, 256, 0, stream>>>(src, dst, nq);
  };
  conv(wq, wq_b, (size_t)DM * DM);
  conv(wk, wk_b, (size_t)DM * DM);
  conv(wv, wv_b, (size_t)DM * DM);
  conv(wo, wo_b, (size_t)DM * DM);
  conv(w1, w1_b, (size_t)DFF * DM);
  conv(w2, w2_b, (size_t)DM * DFF);
  conv(out_proj, wop_b, (size_t)NVOCAB * DM);

  k_embed<<<NTOK, 256, 0, stream>>>(tokens, tok_emb, x);
  k_rmsnorm<<<NTOK, 256, 0, stream>>>(x, attn_nw, xn);

  k_gemm_nt<EPI_BF16><<<(NTOK / 128) * (DM / 128), 256, 0, stream>>>(
      xn, wq_b, NTOK, DM, DM, nullptr, q_b, nullptr);
  k_gemm_nt<EPI_BF16><<<(NTOK / 128) * (DM / 128), 256, 0, stream>>>(
      xn, wk_b, NTOK, DM, DM, nullptr, k_b, nullptr);
  k_gemm_nt<EPI_BF16><<<(NTOK / 128) * (DM / 128), 256, 0, stream>>>(
      xn, wv_b, NTOK, DM, DM, nullptr, v_b, nullptr);

  k_transpose_v<<<32 * 32, 256, 0, stream>>>(v_b, vt_b);
  k_attn<<<32 * 16, 256, 0, stream>>>(q_b, k_b, vt_b, ao_b);

  k_gemm_nt<EPI_RESID><<<(NTOK / 128) * (DM / 128), 256, 0, stream>>>(
      ao_b, wo_b, NTOK, DM, DM, x, nullptr, x);

  k_rmsnorm<<<NTOK, 256, 0, stream>>>(x, ffn_nw, xn);
  k_gemm_nt<EPI_SILU><<<(NTOK / 128) * (DFF / 128), 256, 0, stream>>>(
      xn, w1_b, NTOK, DFF, DM, nullptr, h1_b, nullptr);
  k_gemm_nt<EPI_RESID><<<(NTOK / 128) * (DM / 128), 256, 0, stream>>>(
      h1_b, w2_b, NTOK, DM, DFF, x, nullptr, x);

  k_rmsnorm<<<NTOK, 256, 0, stream>>>(x, final_nw, xn);
  k_gemm_nt<EPI_F32><<<(NTOK / 128) * (NVOCAB / 128), 256, 0, stream>>>(
      xn, wop_b, NTOK, NVOCAB, DM, out, nullptr, nullptr);
}